// Round 1
// baseline (4188.983 us; speedup 1.0000x reference)
//
#include <hip/hip_runtime.h>
#include <hip/hip_bf16.h>

#define NTHREADS 256

// ---------------- degree / normalization ----------------
__global__ void deg_init(float* deg, int n) {
    int i = blockIdx.x * NTHREADS + threadIdx.x;
    if (i < n) deg[i] = 1.0f;  // self-loop
}

__global__ void deg_count(float* deg, const int* __restrict__ ei, int nE) {
    int e = blockIdx.x * NTHREADS + threadIdx.x;
    if (e < nE) atomicAdd(&deg[ei[nE + e]], 1.0f);  // dst = ei[1][e]
}

__global__ void deg_rsqrt(float* deg, int n) {
    int i = blockIdx.x * NTHREADS + threadIdx.x;
    if (i < n) deg[i] = 1.0f / sqrtf(deg[i]);
}

// ---------------- GEMM: out[r][c] = sum_k relu?(in[r][k]) * W[k][c] ----------------
// 64 rows per block, W staged in LDS, in != out guaranteed by caller.
__global__ __launch_bounds__(NTHREADS) void gemm64(
    const float* __restrict__ in, float* __restrict__ out,
    const float* __restrict__ W, int n_rows, int relu_in) {
    __shared__ float sW[64 * 64];
    __shared__ float sX[64 * 64];
    int t = threadIdx.x;

    const float4* W4 = (const float4*)W;
    float4* sW4 = (float4*)sW;
#pragma unroll
    for (int i = 0; i < 4; i++) sW4[t + NTHREADS * i] = W4[t + NTHREADS * i];

    int row_base = blockIdx.x * 64;
    float4* sX4 = (float4*)sX;
#pragma unroll
    for (int i = 0; i < 4; i++) {
        int idx = t + NTHREADS * i;       // float4 slot 0..1023
        int r = row_base + (idx >> 4);
        float4 v = make_float4(0.f, 0.f, 0.f, 0.f);
        if (r < n_rows) v = ((const float4*)(in + (size_t)r * 64))[idx & 15];
        if (relu_in) {
            v.x = fmaxf(v.x, 0.f); v.y = fmaxf(v.y, 0.f);
            v.z = fmaxf(v.z, 0.f); v.w = fmaxf(v.w, 0.f);
        }
        sX4[idx] = v;
    }
    __syncthreads();

    int c = t & 63;
    int r0 = t >> 6;  // 0..3
    float acc[16];
#pragma unroll
    for (int j = 0; j < 16; j++) acc[j] = 0.f;

    for (int k = 0; k < 64; k++) {
        float w = sW[k * 64 + c];
#pragma unroll
        for (int j = 0; j < 16; j++) acc[j] += sX[(r0 + 4 * j) * 64 + k] * w;
    }

#pragma unroll
    for (int j = 0; j < 16; j++) {
        int r = row_base + r0 + 4 * j;
        if (r < n_rows) out[(size_t)r * 64 + c] = acc[j];
    }
}

// ---------------- scatter init: out[i] = bias + T[i]*dis[i]^2 (self-loop) ----------------
__global__ void scatter_init(const float* __restrict__ in, float* __restrict__ out,
                             const float* __restrict__ dis, const float* __restrict__ bias,
                             int n) {
    int idx = blockIdx.x * NTHREADS + threadIdx.x;  // float4 index, n*16 total
    if (idx >= n * 16) return;
    int r = idx >> 4;
    int q = idx & 15;
    float d = dis[r];
    float s = d * d;
    float4 v = ((const float4*)in)[idx];
    float4 b = ((const float4*)bias)[q];
    float4 o;
    o.x = b.x + v.x * s;
    o.y = b.y + v.y * s;
    o.z = b.z + v.z * s;
    o.w = b.w + v.w * s;
    ((float4*)out)[idx] = o;
}

// ---------------- edge scatter: out[dst] += T[src] * dis[src]*dis[dst] ----------------
__global__ void edge_scatter(const float* __restrict__ T, float* __restrict__ out,
                             const float* __restrict__ dis, const int* __restrict__ ei,
                             int nE) {
    int gt = blockIdx.x * NTHREADS + threadIdx.x;   // E*16 threads
    int e = gt >> 4;
    if (e >= nE) return;
    int q = gt & 15;
    int s = ei[e];
    int d = ei[nE + e];
    float nm = dis[s] * dis[d];
    float4 v = ((const float4*)(T + (size_t)s * 64))[q];
    float* o = out + (size_t)d * 64 + q * 4;
    atomicAdd(o + 0, v.x * nm);
    atomicAdd(o + 1, v.y * nm);
    atomicAdd(o + 2, v.z * nm);
    atomicAdd(o + 3, v.w * nm);
}

// ---------------- pooling ----------------
__global__ void zero_pool(float* pooled) {
    int i = blockIdx.x * NTHREADS + threadIdx.x;
    if (i < 64 * 64) pooled[i] = 0.f;
}

__global__ __launch_bounds__(NTHREADS) void pool_kernel(
    const float* __restrict__ h, const int* __restrict__ gid,
    float* __restrict__ pooled, int n) {
    __shared__ float lp[64 * 64];
    int t = threadIdx.x;
    for (int i = t; i < 4096; i += NTHREADS) lp[i] = 0.f;
    __syncthreads();

    int f = t & 63;
    int w = t >> 6;  // 0..3
    int base = blockIdx.x * 1024;
    for (int n0 = 0; n0 < 1024; n0 += 4) {
        int node = base + n0 + w;
        if (node < n) {
            int g = gid[node];
            float v = fmaxf(h[(size_t)node * 64 + f], 0.f);  // relu(conv2 out)
            atomicAdd(&lp[g * 64 + f], v);
        }
    }
    __syncthreads();
    for (int i = t; i < 4096; i += NTHREADS) {
        float v = lp[i];
        if (v != 0.f) atomicAdd(&pooled[i], v);
    }
}

// ---------------- head MLP (one block) ----------------
__global__ __launch_bounds__(NTHREADS) void head_kernel(
    const float* __restrict__ pooled, const float* __restrict__ gf,
    const float* __restrict__ glob_w, const float* __restrict__ glob_b,
    const float* __restrict__ lin1_w, const float* __restrict__ lin1_b,
    const float* __restrict__ lin2_w, const float* __restrict__ lin2_b,
    const float* __restrict__ lin3_w, const float* __restrict__ lin3_b,
    const float* __restrict__ lin4_w, const float* __restrict__ lin4_b,
    float* __restrict__ out) {
    __shared__ float gx[64 * 32];
    __shared__ float zA[64 * 64];
    __shared__ float zB[64 * 64];
    int t = threadIdx.x;

    // gx = relu(gf(64,32) @ glob_w(32,32) + glob_b)
    for (int i = t; i < 64 * 32; i += NTHREADS) {
        int g = i >> 5, j = i & 31;
        float acc = glob_b[j];
        for (int k = 0; k < 32; k++) acc += gf[g * 32 + k] * glob_w[k * 32 + j];
        gx[i] = fmaxf(acc, 0.f);
    }
    // z1 = relu(pooled @ lin1_w + b) -> zA
    for (int i = t; i < 4096; i += NTHREADS) {
        int g = i >> 6, j = i & 63;
        float acc = lin1_b[j];
        for (int k = 0; k < 64; k++) acc += pooled[g * 64 + k] * lin1_w[k * 64 + j];
        zA[i] = fmaxf(acc, 0.f);
    }
    __syncthreads();
    // z2 = relu(cat(zA, gx) @ lin2_w + b) -> zB   (lin2_w is (96,64))
    for (int i = t; i < 4096; i += NTHREADS) {
        int g = i >> 6, j = i & 63;
        float acc = lin2_b[j];
        for (int k = 0; k < 64; k++) acc += zA[g * 64 + k] * lin2_w[k * 64 + j];
        for (int k = 0; k < 32; k++) acc += gx[g * 32 + k] * lin2_w[(64 + k) * 64 + j];
        zB[i] = fmaxf(acc, 0.f);
    }
    __syncthreads();
    // z3 = relu(zB @ lin3_w + b) -> zA (reuse)
    for (int i = t; i < 4096; i += NTHREADS) {
        int g = i >> 6, j = i & 63;
        float acc = lin3_b[j];
        for (int k = 0; k < 64; k++) acc += zB[g * 64 + k] * lin3_w[k * 64 + j];
        zA[i] = fmaxf(acc, 0.f);
    }
    __syncthreads();
    // out = zA @ lin4_w + lin4_b
    if (t < 64) {
        float acc = lin4_b[0];
        for (int k = 0; k < 64; k++) acc += zA[t * 64 + k] * lin4_w[k];
        out[t] = acc;
    }
}

extern "C" void kernel_launch(void* const* d_in, const int* in_sizes, int n_in,
                              void* d_out, int out_size, void* d_ws, size_t ws_size,
                              hipStream_t stream) {
    const float* x      = (const float*)d_in[0];
    const float* gf     = (const float*)d_in[1];
    const float* conv_w[3] = {(const float*)d_in[2], (const float*)d_in[4], (const float*)d_in[6]};
    const float* conv_b[3] = {(const float*)d_in[3], (const float*)d_in[5], (const float*)d_in[7]};
    const float* lin1_w = (const float*)d_in[8];
    const float* lin1_b = (const float*)d_in[9];
    const float* glob_w = (const float*)d_in[10];
    const float* glob_b = (const float*)d_in[11];
    const float* lin2_w = (const float*)d_in[12];
    const float* lin2_b = (const float*)d_in[13];
    const float* lin3_w = (const float*)d_in[14];
    const float* lin3_b = (const float*)d_in[15];
    const float* lin4_w = (const float*)d_in[16];
    const float* lin4_b = (const float*)d_in[17];
    const int* ei  = (const int*)d_in[18];
    const int* gid = (const int*)d_in[19];

    const int N = in_sizes[0] / 64;   // 100000
    const int E = in_sizes[18] / 2;   // 1600000

    float* ws = (float*)d_ws;
    float* dis    = ws;                       // N floats
    float* pooled = dis + N;                  // 4096 floats
    float* T      = pooled + 4096;            // N*64
    float* A      = T + (size_t)N * 64;       // N*64

    // degree + normalization
    deg_init<<<(N + NTHREADS - 1) / NTHREADS, NTHREADS, 0, stream>>>(dis, N);
    deg_count<<<(E + NTHREADS - 1) / NTHREADS, NTHREADS, 0, stream>>>(dis, ei, E);
    deg_rsqrt<<<(N + NTHREADS - 1) / NTHREADS, NTHREADS, 0, stream>>>(dis, N);

    const int gemm_blocks = (N + 63) / 64;
    const int si_blocks = (N * 16 + NTHREADS - 1) / NTHREADS;
    const int es_blocks = (int)(((long long)E * 16 + NTHREADS - 1) / NTHREADS);

    // layer 0: x -> T -> A
    gemm64<<<gemm_blocks, NTHREADS, 0, stream>>>(x, T, conv_w[0], N, 0);
    scatter_init<<<si_blocks, NTHREADS, 0, stream>>>(T, A, dis, conv_b[0], N);
    edge_scatter<<<es_blocks, NTHREADS, 0, stream>>>(T, A, dis, ei, E);

    // layer 1: relu(A) -> T -> A
    gemm64<<<gemm_blocks, NTHREADS, 0, stream>>>(A, T, conv_w[1], N, 1);
    scatter_init<<<si_blocks, NTHREADS, 0, stream>>>(T, A, dis, conv_b[1], N);
    edge_scatter<<<es_blocks, NTHREADS, 0, stream>>>(T, A, dis, ei, E);

    // layer 2: relu(A) -> T -> A
    gemm64<<<gemm_blocks, NTHREADS, 0, stream>>>(A, T, conv_w[2], N, 1);
    scatter_init<<<si_blocks, NTHREADS, 0, stream>>>(T, A, dis, conv_b[2], N);
    edge_scatter<<<es_blocks, NTHREADS, 0, stream>>>(T, A, dis, ei, E);

    // pooling (applies relu to conv2 output)
    zero_pool<<<16, NTHREADS, 0, stream>>>(pooled);
    pool_kernel<<<(N + 1023) / 1024, NTHREADS, 0, stream>>>(A, gid, pooled, N);

    // head MLP
    head_kernel<<<1, NTHREADS, 0, stream>>>(pooled, gf,
                                            glob_w, glob_b, lin1_w, lin1_b,
                                            lin2_w, lin2_b, lin3_w, lin3_b,
                                            lin4_w, lin4_b, (float*)d_out);
}

// Round 2
// 614.648 us; speedup vs baseline: 6.8153x; 6.8153x over previous
//
#include <hip/hip_runtime.h>
#include <hip/hip_bf16.h>

#define NTHREADS 256

// ---------------- CSR build ----------------
__global__ void zero_int(int* p, int n) {
    int i = blockIdx.x * NTHREADS + threadIdx.x;
    if (i < n) p[i] = 0;
}

__global__ void hist_dst(int* degi, const int* __restrict__ ei, int nE) {
    int e = blockIdx.x * NTHREADS + threadIdx.x;
    if (e < nE) atomicAdd(&degi[ei[nE + e]], 1);  // dst = ei[1][e]
}

__global__ void dis_kernel(const int* __restrict__ degi, float* dis, int n) {
    int i = blockIdx.x * NTHREADS + threadIdx.x;
    if (i < n) dis[i] = rsqrtf(1.0f + (float)degi[i]);  // +1 self-loop
}

// scan1: per-block (1024 elems) exclusive scan of degi -> row_ptr(local), block sums
__global__ __launch_bounds__(NTHREADS) void scan1(const int* __restrict__ degi,
                                                  int* row_ptr, int* bsums, int n) {
    __shared__ int part[NTHREADS];
    int t = threadIdx.x;
    int base = blockIdx.x * 1024 + t * 4;
    int v[4];
    int s = 0;
#pragma unroll
    for (int j = 0; j < 4; j++) {
        v[j] = (base + j < n) ? degi[base + j] : 0;
        s += v[j];
    }
    part[t] = s;
    __syncthreads();
    for (int off = 1; off < NTHREADS; off <<= 1) {
        int x = (t >= off) ? part[t - off] : 0;
        __syncthreads();
        part[t] += x;
        __syncthreads();
    }
    int excl = (t == 0) ? 0 : part[t - 1];
#pragma unroll
    for (int j = 0; j < 4; j++) {
        if (base + j < n) row_ptr[base + j] = excl;
        excl += v[j];
    }
    if (t == NTHREADS - 1) bsums[blockIdx.x] = part[NTHREADS - 1];
}

__global__ void scan2(int* bsums, int nb) {
    if (threadIdx.x == 0 && blockIdx.x == 0) {
        int run = 0;
        for (int i = 0; i < nb; i++) { int v = bsums[i]; bsums[i] = run; run += v; }
    }
}

__global__ void scan3(int* row_ptr, int* cursor, const int* __restrict__ bsums,
                      int n, int nE) {
    int i = blockIdx.x * NTHREADS + threadIdx.x;
    if (i < n) {
        int v = row_ptr[i] + bsums[i >> 10];
        row_ptr[i] = v;
        cursor[i] = v;
    }
    if (i == 0) row_ptr[n] = nE;
}

__global__ void bucket(const int* __restrict__ ei, const float* __restrict__ dis,
                       int* cursor, int* col, float* wgt, int nE) {
    int e = blockIdx.x * NTHREADS + threadIdx.x;
    if (e >= nE) return;
    int s = ei[e];
    int d = ei[nE + e];
    int pos = atomicAdd(&cursor[d], 1);
    col[pos] = s;
    wgt[pos] = dis[s] * dis[d];
}

// ---------------- GEMM: out[r][c] = sum_k relu?(in[r][k]) * W[k][c] ----------------
__global__ __launch_bounds__(NTHREADS) void gemm64(
    const float* __restrict__ in, float* __restrict__ out,
    const float* __restrict__ W, int n_rows, int relu_in) {
    __shared__ float sW[64 * 64];
    __shared__ float sX[64 * 64];
    int t = threadIdx.x;

    const float4* W4 = (const float4*)W;
    float4* sW4 = (float4*)sW;
#pragma unroll
    for (int i = 0; i < 4; i++) sW4[t + NTHREADS * i] = W4[t + NTHREADS * i];

    int row_base = blockIdx.x * 64;
    float4* sX4 = (float4*)sX;
#pragma unroll
    for (int i = 0; i < 4; i++) {
        int idx = t + NTHREADS * i;
        int r = row_base + (idx >> 4);
        float4 v = make_float4(0.f, 0.f, 0.f, 0.f);
        if (r < n_rows) v = ((const float4*)(in + (size_t)r * 64))[idx & 15];
        if (relu_in) {
            v.x = fmaxf(v.x, 0.f); v.y = fmaxf(v.y, 0.f);
            v.z = fmaxf(v.z, 0.f); v.w = fmaxf(v.w, 0.f);
        }
        sX4[idx] = v;
    }
    __syncthreads();

    int c = t & 63;
    int r0 = t >> 6;
    float acc[16];
#pragma unroll
    for (int j = 0; j < 16; j++) acc[j] = 0.f;

    for (int k = 0; k < 64; k++) {
        float w = sW[k * 64 + c];
#pragma unroll
        for (int j = 0; j < 16; j++) acc[j] += sX[(r0 + 4 * j) * 64 + k] * w;
    }

#pragma unroll
    for (int j = 0; j < 16; j++) {
        int r = row_base + r0 + 4 * j;
        if (r < n_rows) out[(size_t)r * 64 + c] = acc[j];
    }
}

// ---------------- fused GCN aggregate: out[n] = bias + self + sum_in-edges ----------------
// 16 lanes per node, float4 per lane (64 feats).
__global__ __launch_bounds__(NTHREADS) void gcn_aggregate(
    const float* __restrict__ T, float* __restrict__ out,
    const float* __restrict__ dis, const float* __restrict__ bias,
    const int* __restrict__ row_ptr, const int* __restrict__ col,
    const float* __restrict__ wgt, int n) {
    int node = (blockIdx.x * NTHREADS + threadIdx.x) >> 4;
    int q = threadIdx.x & 15;
    if (node >= n) return;

    const float4* T4 = (const float4*)T;
    float4 b = ((const float4*)bias)[q];
    float dn = dis[node];
    float s2 = dn * dn;
    float4 v = T4[(size_t)node * 16 + q];
    float4 acc;
    acc.x = b.x + v.x * s2;
    acc.y = b.y + v.y * s2;
    acc.z = b.z + v.z * s2;
    acc.w = b.w + v.w * s2;

    int e0 = row_ptr[node];
    int e1 = row_ptr[node + 1];
    int e = e0;
    // 2-deep unroll for load latency hiding
    for (; e + 1 < e1; e += 2) {
        int s0 = col[e], s1 = col[e + 1];
        float w0 = wgt[e], w1 = wgt[e + 1];
        float4 t0 = T4[(size_t)s0 * 16 + q];
        float4 t1 = T4[(size_t)s1 * 16 + q];
        acc.x += t0.x * w0; acc.y += t0.y * w0; acc.z += t0.z * w0; acc.w += t0.w * w0;
        acc.x += t1.x * w1; acc.y += t1.y * w1; acc.z += t1.z * w1; acc.w += t1.w * w1;
    }
    if (e < e1) {
        int s0 = col[e];
        float w0 = wgt[e];
        float4 t0 = T4[(size_t)s0 * 16 + q];
        acc.x += t0.x * w0; acc.y += t0.y * w0; acc.z += t0.z * w0; acc.w += t0.w * w0;
    }
    ((float4*)out)[(size_t)node * 16 + q] = acc;
}

// ---------------- pooling ----------------
__global__ void zero_pool(float* pooled) {
    int i = blockIdx.x * NTHREADS + threadIdx.x;
    if (i < 64 * 64) pooled[i] = 0.f;
}

__global__ __launch_bounds__(NTHREADS) void pool_kernel(
    const float* __restrict__ h, const int* __restrict__ gid,
    float* __restrict__ pooled, int n) {
    __shared__ float lp[64 * 64];
    int t = threadIdx.x;
    for (int i = t; i < 4096; i += NTHREADS) lp[i] = 0.f;
    __syncthreads();

    int f = t & 63;
    int w = t >> 6;
    int base = blockIdx.x * 1024;
    for (int n0 = 0; n0 < 1024; n0 += 4) {
        int node = base + n0 + w;
        if (node < n) {
            int g = gid[node];
            float v = fmaxf(h[(size_t)node * 64 + f], 0.f);  // relu(conv2 out)
            atomicAdd(&lp[g * 64 + f], v);
        }
    }
    __syncthreads();
    for (int i = t; i < 4096; i += NTHREADS) {
        float v = lp[i];
        if (v != 0.f) atomicAdd(&pooled[i], v);
    }
}

// ---------------- head MLP (one block) ----------------
__global__ __launch_bounds__(NTHREADS) void head_kernel(
    const float* __restrict__ pooled, const float* __restrict__ gf,
    const float* __restrict__ glob_w, const float* __restrict__ glob_b,
    const float* __restrict__ lin1_w, const float* __restrict__ lin1_b,
    const float* __restrict__ lin2_w, const float* __restrict__ lin2_b,
    const float* __restrict__ lin3_w, const float* __restrict__ lin3_b,
    const float* __restrict__ lin4_w, const float* __restrict__ lin4_b,
    float* __restrict__ out) {
    __shared__ float gx[64 * 32];
    __shared__ float zA[64 * 64];
    __shared__ float zB[64 * 64];
    int t = threadIdx.x;

    for (int i = t; i < 64 * 32; i += NTHREADS) {
        int g = i >> 5, j = i & 31;
        float acc = glob_b[j];
        for (int k = 0; k < 32; k++) acc += gf[g * 32 + k] * glob_w[k * 32 + j];
        gx[i] = fmaxf(acc, 0.f);
    }
    for (int i = t; i < 4096; i += NTHREADS) {
        int g = i >> 6, j = i & 63;
        float acc = lin1_b[j];
        for (int k = 0; k < 64; k++) acc += pooled[g * 64 + k] * lin1_w[k * 64 + j];
        zA[i] = fmaxf(acc, 0.f);
    }
    __syncthreads();
    for (int i = t; i < 4096; i += NTHREADS) {
        int g = i >> 6, j = i & 63;
        float acc = lin2_b[j];
        for (int k = 0; k < 64; k++) acc += zA[g * 64 + k] * lin2_w[k * 64 + j];
        for (int k = 0; k < 32; k++) acc += gx[g * 32 + k] * lin2_w[(64 + k) * 64 + j];
        zB[i] = fmaxf(acc, 0.f);
    }
    __syncthreads();
    for (int i = t; i < 4096; i += NTHREADS) {
        int g = i >> 6, j = i & 63;
        float acc = lin3_b[j];
        for (int k = 0; k < 64; k++) acc += zB[g * 64 + k] * lin3_w[k * 64 + j];
        zA[i] = fmaxf(acc, 0.f);
    }
    __syncthreads();
    if (t < 64) {
        float acc = lin4_b[0];
        for (int k = 0; k < 64; k++) acc += zA[t * 64 + k] * lin4_w[k];
        out[t] = acc;
    }
}

extern "C" void kernel_launch(void* const* d_in, const int* in_sizes, int n_in,
                              void* d_out, int out_size, void* d_ws, size_t ws_size,
                              hipStream_t stream) {
    const float* x      = (const float*)d_in[0];
    const float* gf     = (const float*)d_in[1];
    const float* conv_w[3] = {(const float*)d_in[2], (const float*)d_in[4], (const float*)d_in[6]};
    const float* conv_b[3] = {(const float*)d_in[3], (const float*)d_in[5], (const float*)d_in[7]};
    const float* lin1_w = (const float*)d_in[8];
    const float* lin1_b = (const float*)d_in[9];
    const float* glob_w = (const float*)d_in[10];
    const float* glob_b = (const float*)d_in[11];
    const float* lin2_w = (const float*)d_in[12];
    const float* lin2_b = (const float*)d_in[13];
    const float* lin3_w = (const float*)d_in[14];
    const float* lin3_b = (const float*)d_in[15];
    const float* lin4_w = (const float*)d_in[16];
    const float* lin4_b = (const float*)d_in[17];
    const int* ei  = (const int*)d_in[18];
    const int* gid = (const int*)d_in[19];

    const int N = in_sizes[0] / 64;   // 100000
    const int E = in_sizes[18] / 2;   // 1600000

    // workspace layout
    char* ws = (char*)d_ws;
    float* dis     = (float*)ws;                      ws += (size_t)N * 4;
    float* pooled  = (float*)ws;                      ws += 4096 * 4;
    float* T       = (float*)ws;                      ws += (size_t)N * 64 * 4;
    float* A       = (float*)ws;                      ws += (size_t)N * 64 * 4;
    int*   degi    = (int*)ws;                        ws += (size_t)N * 4;
    int*   row_ptr = (int*)ws;                        ws += ((size_t)N + 1) * 4;
    int*   cursor  = (int*)ws;                        ws += (size_t)N * 4;
    int*   col     = (int*)ws;                        ws += (size_t)E * 4;
    float* wgt     = (float*)ws;                      ws += (size_t)E * 4;
    int*   bsums   = (int*)ws;                        ws += 512 * 4;

    const int nb_N  = (N + NTHREADS - 1) / NTHREADS;
    const int nb_E  = (E + NTHREADS - 1) / NTHREADS;
    const int nb_sc = (N + 1023) / 1024;

    // ---- CSR build ----
    zero_int<<<nb_N, NTHREADS, 0, stream>>>(degi, N);
    hist_dst<<<nb_E, NTHREADS, 0, stream>>>(degi, ei, E);
    dis_kernel<<<nb_N, NTHREADS, 0, stream>>>(degi, dis, N);
    scan1<<<nb_sc, NTHREADS, 0, stream>>>(degi, row_ptr, bsums, N);
    scan2<<<1, 64, 0, stream>>>(bsums, nb_sc);
    scan3<<<nb_N, NTHREADS, 0, stream>>>(row_ptr, cursor, bsums, N, E);
    bucket<<<nb_E, NTHREADS, 0, stream>>>(ei, dis, cursor, col, wgt, E);

    const int gemm_blocks = (N + 63) / 64;
    const int agg_blocks  = (N * 16 + NTHREADS - 1) / NTHREADS;

    // layer 0: x -> T -> A
    gemm64<<<gemm_blocks, NTHREADS, 0, stream>>>(x, T, conv_w[0], N, 0);
    gcn_aggregate<<<agg_blocks, NTHREADS, 0, stream>>>(T, A, dis, conv_b[0], row_ptr, col, wgt, N);

    // layer 1: relu(A) -> T -> A
    gemm64<<<gemm_blocks, NTHREADS, 0, stream>>>(A, T, conv_w[1], N, 1);
    gcn_aggregate<<<agg_blocks, NTHREADS, 0, stream>>>(T, A, dis, conv_b[1], row_ptr, col, wgt, N);

    // layer 2: relu(A) -> T -> A
    gemm64<<<gemm_blocks, NTHREADS, 0, stream>>>(A, T, conv_w[2], N, 1);
    gcn_aggregate<<<agg_blocks, NTHREADS, 0, stream>>>(T, A, dis, conv_b[2], row_ptr, col, wgt, N);

    // pooling (applies relu to conv2 output)
    zero_pool<<<16, NTHREADS, 0, stream>>>(pooled);
    pool_kernel<<<(N + 1023) / 1024, NTHREADS, 0, stream>>>(A, gid, pooled, N);

    // head MLP
    head_kernel<<<1, NTHREADS, 0, stream>>>(pooled, gf,
                                            glob_w, glob_b, lin1_w, lin1_b,
                                            lin2_w, lin2_b, lin3_w, lin3_b,
                                            lin4_w, lin4_b, (float*)d_out);
}

// Round 3
// 559.503 us; speedup vs baseline: 7.4870x; 1.0986x over previous
//
#include <hip/hip_runtime.h>
#include <hip/hip_bf16.h>

#define NTHREADS 256

typedef unsigned int uint32;

// ---------------- CSR build ----------------
__global__ void hist_dst(int* degi, const int* __restrict__ ei, int nE) {
    int e = blockIdx.x * NTHREADS + threadIdx.x;
    if (e < nE) atomicAdd(&degi[ei[nE + e]], 1);  // dst = ei[1][e]
}

__global__ void dis_kernel(const int* __restrict__ degi, float* dis, int n) {
    int i = blockIdx.x * NTHREADS + threadIdx.x;
    if (i < n) dis[i] = rsqrtf(1.0f + (float)degi[i]);  // +1 self-loop
}

// scan1: per-block (1024 elems) exclusive scan of degi -> row_ptr(local), block sums
__global__ __launch_bounds__(NTHREADS) void scan1(const int* __restrict__ degi,
                                                  int* row_ptr, int* bsums, int n) {
    __shared__ int part[NTHREADS];
    int t = threadIdx.x;
    int base = blockIdx.x * 1024 + t * 4;
    int v[4];
    int s = 0;
#pragma unroll
    for (int j = 0; j < 4; j++) {
        v[j] = (base + j < n) ? degi[base + j] : 0;
        s += v[j];
    }
    part[t] = s;
    __syncthreads();
    for (int off = 1; off < NTHREADS; off <<= 1) {
        int x = (t >= off) ? part[t - off] : 0;
        __syncthreads();
        part[t] += x;
        __syncthreads();
    }
    int excl = (t == 0) ? 0 : part[t - 1];
#pragma unroll
    for (int j = 0; j < 4; j++) {
        if (base + j < n) row_ptr[base + j] = excl;
        excl += v[j];
    }
    if (t == NTHREADS - 1) bsums[blockIdx.x] = part[NTHREADS - 1];
}

__global__ void scan2(int* bsums, int nb) {
    if (threadIdx.x == 0 && blockIdx.x == 0) {
        int run = 0;
        for (int i = 0; i < nb; i++) { int v = bsums[i]; bsums[i] = run; run += v; }
    }
}

__global__ void scan3(int* row_ptr, int* cursor, const int* __restrict__ bsums,
                      int n, int nE) {
    int i = blockIdx.x * NTHREADS + threadIdx.x;
    if (i < n) {
        int v = row_ptr[i] + bsums[i >> 10];
        row_ptr[i] = v;
        cursor[i] = v;
    }
    if (i == 0) row_ptr[n] = nE;
}

// bucket: one packed 8B write per edge, 2 edges per thread for ILP
__global__ void bucket(const int* __restrict__ ei, const float* __restrict__ dis,
                       int* cursor, int2* __restrict__ adj, int nE) {
    int base = (blockIdx.x * NTHREADS + threadIdx.x) * 2;
#pragma unroll
    for (int j = 0; j < 2; j++) {
        int e = base + j;
        if (e < nE) {
            int s = ei[e];
            int d = ei[nE + e];
            float w = dis[s] * dis[d];
            int pos = atomicAdd(&cursor[d], 1);
            adj[pos] = make_int2(s, __float_as_int(w));
        }
    }
}

// ---------------- GEMM: T[r][c] = bf16( sum_k relu?(in[r][k]) * W[k][c] ) ----------------
__global__ __launch_bounds__(NTHREADS) void gemm64(
    const float* __restrict__ in, __hip_bfloat16* __restrict__ out,
    const float* __restrict__ W, int n_rows, int relu_in) {
    __shared__ float sW[64 * 64];
    __shared__ float sX[64 * 64];
    int t = threadIdx.x;

    const float4* W4 = (const float4*)W;
    float4* sW4 = (float4*)sW;
#pragma unroll
    for (int i = 0; i < 4; i++) sW4[t + NTHREADS * i] = W4[t + NTHREADS * i];

    int row_base = blockIdx.x * 64;
    float4* sX4 = (float4*)sX;
#pragma unroll
    for (int i = 0; i < 4; i++) {
        int idx = t + NTHREADS * i;
        int r = row_base + (idx >> 4);
        float4 v = make_float4(0.f, 0.f, 0.f, 0.f);
        if (r < n_rows) v = ((const float4*)(in + (size_t)r * 64))[idx & 15];
        if (relu_in) {
            v.x = fmaxf(v.x, 0.f); v.y = fmaxf(v.y, 0.f);
            v.z = fmaxf(v.z, 0.f); v.w = fmaxf(v.w, 0.f);
        }
        sX4[idx] = v;
    }
    __syncthreads();

    int c = t & 63;
    int r0 = t >> 6;
    float acc[16];
#pragma unroll
    for (int j = 0; j < 16; j++) acc[j] = 0.f;

    for (int k = 0; k < 64; k++) {
        float w = sW[k * 64 + c];
#pragma unroll
        for (int j = 0; j < 16; j++) acc[j] += sX[(r0 + 4 * j) * 64 + k] * w;
    }

#pragma unroll
    for (int j = 0; j < 16; j++) {
        int r = row_base + r0 + 4 * j;
        if (r < n_rows) out[(size_t)r * 64 + c] = __float2bfloat16(acc[j]);
    }
}

// ---------------- fused GCN aggregate: out[n] = bias + self + sum_in-edges ----------------
// 16 lanes per node; T is bf16 (8B = 4 feats per lane).
__global__ __launch_bounds__(NTHREADS) void gcn_aggregate(
    const __hip_bfloat16* __restrict__ T, float* __restrict__ out,
    const float* __restrict__ dis, const float* __restrict__ bias,
    const int* __restrict__ row_ptr, const int2* __restrict__ adj, int n) {
    int node = (blockIdx.x * NTHREADS + threadIdx.x) >> 4;
    int q = threadIdx.x & 15;
    if (node >= n) return;

    const ushort4* T4 = (const ushort4*)T;  // 4 bf16 per load
    float4 b = ((const float4*)bias)[q];
    float dn = dis[node];
    float s2 = dn * dn;

    ushort4 sv = T4[(size_t)node * 16 + q];
    float4 acc;
    acc.x = b.x + __uint_as_float((uint32)sv.x << 16) * s2;
    acc.y = b.y + __uint_as_float((uint32)sv.y << 16) * s2;
    acc.z = b.z + __uint_as_float((uint32)sv.z << 16) * s2;
    acc.w = b.w + __uint_as_float((uint32)sv.w << 16) * s2;

    int e0 = row_ptr[node];
    int e1 = row_ptr[node + 1];
    int e = e0;
    for (; e + 1 < e1; e += 2) {
        int2 a0 = adj[e];
        int2 a1 = adj[e + 1];
        float w0 = __int_as_float(a0.y);
        float w1 = __int_as_float(a1.y);
        ushort4 t0 = T4[(size_t)a0.x * 16 + q];
        ushort4 t1 = T4[(size_t)a1.x * 16 + q];
        acc.x += __uint_as_float((uint32)t0.x << 16) * w0;
        acc.y += __uint_as_float((uint32)t0.y << 16) * w0;
        acc.z += __uint_as_float((uint32)t0.z << 16) * w0;
        acc.w += __uint_as_float((uint32)t0.w << 16) * w0;
        acc.x += __uint_as_float((uint32)t1.x << 16) * w1;
        acc.y += __uint_as_float((uint32)t1.y << 16) * w1;
        acc.z += __uint_as_float((uint32)t1.z << 16) * w1;
        acc.w += __uint_as_float((uint32)t1.w << 16) * w1;
    }
    if (e < e1) {
        int2 a0 = adj[e];
        float w0 = __int_as_float(a0.y);
        ushort4 t0 = T4[(size_t)a0.x * 16 + q];
        acc.x += __uint_as_float((uint32)t0.x << 16) * w0;
        acc.y += __uint_as_float((uint32)t0.y << 16) * w0;
        acc.z += __uint_as_float((uint32)t0.z << 16) * w0;
        acc.w += __uint_as_float((uint32)t0.w << 16) * w0;
    }
    ((float4*)out)[(size_t)node * 16 + q] = acc;
}

// ---------------- pooling (gid sorted -> register run-length accumulation) ----------------
__global__ __launch_bounds__(NTHREADS) void pool_kernel(
    const float* __restrict__ h, const int* __restrict__ gid,
    float* __restrict__ pooled, int n) {
    __shared__ float lp[64 * 64];
    int t = threadIdx.x;
    for (int i = t; i < 4096; i += NTHREADS) lp[i] = 0.f;
    __syncthreads();

    int f = t & 63;
    int w = t >> 6;
    int base = blockIdx.x * 1024;
    float racc = 0.f;
    int cur = -1;
    for (int n0 = 0; n0 < 1024; n0 += 4) {
        int node = base + n0 + w;
        if (node < n) {
            int g = gid[node];
            if (g != cur) {
                if (cur >= 0 && racc != 0.f) atomicAdd(&lp[cur * 64 + f], racc);
                racc = 0.f;
                cur = g;
            }
            racc += fmaxf(h[(size_t)node * 64 + f], 0.f);  // relu(conv2 out)
        }
    }
    if (cur >= 0 && racc != 0.f) atomicAdd(&lp[cur * 64 + f], racc);
    __syncthreads();
    for (int i = t; i < 4096; i += NTHREADS) {
        float v = lp[i];
        if (v != 0.f) atomicAdd(&pooled[i], v);
    }
}

// ---------------- head MLP (one block) ----------------
__global__ __launch_bounds__(NTHREADS) void head_kernel(
    const float* __restrict__ pooled, const float* __restrict__ gf,
    const float* __restrict__ glob_w, const float* __restrict__ glob_b,
    const float* __restrict__ lin1_w, const float* __restrict__ lin1_b,
    const float* __restrict__ lin2_w, const float* __restrict__ lin2_b,
    const float* __restrict__ lin3_w, const float* __restrict__ lin3_b,
    const float* __restrict__ lin4_w, const float* __restrict__ lin4_b,
    float* __restrict__ out) {
    __shared__ float gx[64 * 32];
    __shared__ float zA[64 * 64];
    __shared__ float zB[64 * 64];
    int t = threadIdx.x;

    for (int i = t; i < 64 * 32; i += NTHREADS) {
        int g = i >> 5, j = i & 31;
        float acc = glob_b[j];
        for (int k = 0; k < 32; k++) acc += gf[g * 32 + k] * glob_w[k * 32 + j];
        gx[i] = fmaxf(acc, 0.f);
    }
    for (int i = t; i < 4096; i += NTHREADS) {
        int g = i >> 6, j = i & 63;
        float acc = lin1_b[j];
        for (int k = 0; k < 64; k++) acc += pooled[g * 64 + k] * lin1_w[k * 64 + j];
        zA[i] = fmaxf(acc, 0.f);
    }
    __syncthreads();
    for (int i = t; i < 4096; i += NTHREADS) {
        int g = i >> 6, j = i & 63;
        float acc = lin2_b[j];
        for (int k = 0; k < 64; k++) acc += zA[g * 64 + k] * lin2_w[k * 64 + j];
        for (int k = 0; k < 32; k++) acc += gx[g * 32 + k] * lin2_w[(64 + k) * 64 + j];
        zB[i] = fmaxf(acc, 0.f);
    }
    __syncthreads();
    for (int i = t; i < 4096; i += NTHREADS) {
        int g = i >> 6, j = i & 63;
        float acc = lin3_b[j];
        for (int k = 0; k < 64; k++) acc += zB[g * 64 + k] * lin3_w[k * 64 + j];
        zA[i] = fmaxf(acc, 0.f);
    }
    __syncthreads();
    if (t < 64) {
        float acc = lin4_b[0];
        for (int k = 0; k < 64; k++) acc += zA[t * 64 + k] * lin4_w[k];
        out[t] = acc;
    }
}

extern "C" void kernel_launch(void* const* d_in, const int* in_sizes, int n_in,
                              void* d_out, int out_size, void* d_ws, size_t ws_size,
                              hipStream_t stream) {
    const float* x      = (const float*)d_in[0];
    const float* gf     = (const float*)d_in[1];
    const float* conv_w[3] = {(const float*)d_in[2], (const float*)d_in[4], (const float*)d_in[6]};
    const float* conv_b[3] = {(const float*)d_in[3], (const float*)d_in[5], (const float*)d_in[7]};
    const float* lin1_w = (const float*)d_in[8];
    const float* lin1_b = (const float*)d_in[9];
    const float* glob_w = (const float*)d_in[10];
    const float* glob_b = (const float*)d_in[11];
    const float* lin2_w = (const float*)d_in[12];
    const float* lin2_b = (const float*)d_in[13];
    const float* lin3_w = (const float*)d_in[14];
    const float* lin3_b = (const float*)d_in[15];
    const float* lin4_w = (const float*)d_in[16];
    const float* lin4_b = (const float*)d_in[17];
    const int* ei  = (const int*)d_in[18];
    const int* gid = (const int*)d_in[19];

    const int N = in_sizes[0] / 64;   // 100000
    const int E = in_sizes[18] / 2;   // 1600000

    // workspace layout (keep every segment 16B-aligned)
    char* ws = (char*)d_ws;
    float* dis     = (float*)ws;                 ws += (size_t)N * 4;
    float* pooled  = (float*)ws;                 ws += 4096 * 4;
    __hip_bfloat16* T = (__hip_bfloat16*)ws;     ws += (size_t)N * 64 * 2;
    float* A       = (float*)ws;                 ws += (size_t)N * 64 * 4;
    int*   degi    = (int*)ws;                   ws += (size_t)N * 4;
    int*   row_ptr = (int*)ws;                   ws += ((size_t)N + 4) * 4;
    int*   cursor  = (int*)ws;                   ws += (size_t)N * 4;
    int2*  adj     = (int2*)ws;                  ws += (size_t)E * 8;
    int*   bsums   = (int*)ws;                   ws += 512 * 4;

    const int nb_N  = (N + NTHREADS - 1) / NTHREADS;
    const int nb_E  = (E + NTHREADS - 1) / NTHREADS;
    const int nb_E2 = (E / 2 + NTHREADS - 1) / NTHREADS;
    const int nb_sc = (N + 1023) / 1024;

    // ---- CSR build ----
    hipMemsetAsync(degi, 0, (size_t)N * 4, stream);
    hist_dst<<<nb_E, NTHREADS, 0, stream>>>(degi, ei, E);
    dis_kernel<<<nb_N, NTHREADS, 0, stream>>>(degi, dis, N);
    scan1<<<nb_sc, NTHREADS, 0, stream>>>(degi, row_ptr, bsums, N);
    scan2<<<1, 64, 0, stream>>>(bsums, nb_sc);
    scan3<<<nb_N, NTHREADS, 0, stream>>>(row_ptr, cursor, bsums, N, E);
    bucket<<<nb_E2, NTHREADS, 0, stream>>>(ei, dis, cursor, adj, E);

    const int gemm_blocks = (N + 63) / 64;
    const int agg_blocks  = (N * 16 + NTHREADS - 1) / NTHREADS;

    // layer 0: x -> T -> A
    gemm64<<<gemm_blocks, NTHREADS, 0, stream>>>(x, T, conv_w[0], N, 0);
    gcn_aggregate<<<agg_blocks, NTHREADS, 0, stream>>>(T, A, dis, conv_b[0], row_ptr, adj, N);

    // layer 1: relu(A) -> T -> A
    gemm64<<<gemm_blocks, NTHREADS, 0, stream>>>(A, T, conv_w[1], N, 1);
    gcn_aggregate<<<agg_blocks, NTHREADS, 0, stream>>>(T, A, dis, conv_b[1], row_ptr, adj, N);

    // layer 2: relu(A) -> T -> A
    gemm64<<<gemm_blocks, NTHREADS, 0, stream>>>(A, T, conv_w[2], N, 1);
    gcn_aggregate<<<agg_blocks, NTHREADS, 0, stream>>>(T, A, dis, conv_b[2], row_ptr, adj, N);

    // pooling (applies relu to conv2 output)
    hipMemsetAsync(pooled, 0, 4096 * 4, stream);
    pool_kernel<<<(N + 1023) / 1024, NTHREADS, 0, stream>>>(A, gid, pooled, N);

    // head MLP
    head_kernel<<<1, NTHREADS, 0, stream>>>(pooled, gf,
                                            glob_w, glob_b, lin1_w, lin1_b,
                                            lin2_w, lin2_b, lin3_w, lin3_b,
                                            lin4_w, lin4_b, (float*)d_out);
}

// Round 4
// 477.021 us; speedup vs baseline: 8.7815x; 1.1729x over previous
//
#include <hip/hip_runtime.h>
#include <hip/hip_bf16.h>

#define NTHREADS 256

typedef unsigned int uint32;

// ---------------- CSR build ----------------
__global__ void hist_dst(int* degi, const int* __restrict__ ei, int nE) {
    int base = (blockIdx.x * NTHREADS + threadIdx.x) * 2;
#pragma unroll
    for (int j = 0; j < 2; j++) {
        int e = base + j;
        if (e < nE) atomicAdd(&degi[ei[nE + e]], 1);  // dst = ei[1][e]
    }
}

__global__ void dis_kernel(const int* __restrict__ degi, float* dis, int n) {
    int i = blockIdx.x * NTHREADS + threadIdx.x;
    if (i < n) dis[i] = rsqrtf(1.0f + (float)degi[i]);  // +1 self-loop
}

// scan1: per-block (1024 elems) exclusive scan of degi -> row_ptr(local), block sums
__global__ __launch_bounds__(NTHREADS) void scan1(const int* __restrict__ degi,
                                                  int* row_ptr, int* bsums, int n) {
    __shared__ int part[NTHREADS];
    int t = threadIdx.x;
    int base = blockIdx.x * 1024 + t * 4;
    int v[4];
    int s = 0;
#pragma unroll
    for (int j = 0; j < 4; j++) {
        v[j] = (base + j < n) ? degi[base + j] : 0;
        s += v[j];
    }
    part[t] = s;
    __syncthreads();
    for (int off = 1; off < NTHREADS; off <<= 1) {
        int x = (t >= off) ? part[t - off] : 0;
        __syncthreads();
        part[t] += x;
        __syncthreads();
    }
    int excl = (t == 0) ? 0 : part[t - 1];
#pragma unroll
    for (int j = 0; j < 4; j++) {
        if (base + j < n) row_ptr[base + j] = excl;
        excl += v[j];
    }
    if (t == NTHREADS - 1) bsums[blockIdx.x] = part[NTHREADS - 1];
}

__global__ void scan2(int* bsums, int nb) {
    if (threadIdx.x == 0 && blockIdx.x == 0) {
        int run = 0;
        for (int i = 0; i < nb; i++) { int v = bsums[i]; bsums[i] = run; run += v; }
    }
}

__global__ void scan3(int* row_ptr, int* cursor, const int* __restrict__ bsums,
                      int n, int nE) {
    int i = blockIdx.x * NTHREADS + threadIdx.x;
    if (i < n) {
        int v = row_ptr[i] + bsums[i >> 10];
        row_ptr[i] = v;
        cursor[i] = v;
    }
    if (i == 0) row_ptr[n] = nE;
}

// bucket: one packed 8B write per edge, 4 edges per thread for MLP
__global__ void bucket(const int* __restrict__ ei, const float* __restrict__ dis,
                       int* cursor, int2* __restrict__ adj, int nE) {
    int base = (blockIdx.x * NTHREADS + threadIdx.x) * 4;
#pragma unroll
    for (int j = 0; j < 4; j++) {
        int e = base + j;
        if (e < nE) {
            int s = ei[e];
            int d = ei[nE + e];
            float w = dis[s] * dis[d];
            int pos = atomicAdd(&cursor[d], 1);
            adj[pos] = make_int2(s, __float_as_int(w));
        }
    }
}

// ---------------- GEMM: T[r][c] = bf16( sum_k relu?(in[r][k]) * W[k][c] ) ----------------
__global__ __launch_bounds__(NTHREADS) void gemm64(
    const float* __restrict__ in, __hip_bfloat16* __restrict__ out,
    const float* __restrict__ W, int n_rows, int relu_in) {
    __shared__ float sW[64 * 64];
    __shared__ float sX[64 * 64];
    int t = threadIdx.x;

    const float4* W4 = (const float4*)W;
    float4* sW4 = (float4*)sW;
#pragma unroll
    for (int i = 0; i < 4; i++) sW4[t + NTHREADS * i] = W4[t + NTHREADS * i];

    int row_base = blockIdx.x * 64;
    float4* sX4 = (float4*)sX;
#pragma unroll
    for (int i = 0; i < 4; i++) {
        int idx = t + NTHREADS * i;
        int r = row_base + (idx >> 4);
        float4 v = make_float4(0.f, 0.f, 0.f, 0.f);
        if (r < n_rows) v = ((const float4*)(in + (size_t)r * 64))[idx & 15];
        if (relu_in) {
            v.x = fmaxf(v.x, 0.f); v.y = fmaxf(v.y, 0.f);
            v.z = fmaxf(v.z, 0.f); v.w = fmaxf(v.w, 0.f);
        }
        sX4[idx] = v;
    }
    __syncthreads();

    int c = t & 63;
    int r0 = t >> 6;
    float acc[16];
#pragma unroll
    for (int j = 0; j < 16; j++) acc[j] = 0.f;

    for (int k = 0; k < 64; k++) {
        float w = sW[k * 64 + c];
#pragma unroll
        for (int j = 0; j < 16; j++) acc[j] += sX[(r0 + 4 * j) * 64 + k] * w;
    }

#pragma unroll
    for (int j = 0; j < 16; j++) {
        int r = row_base + r0 + 4 * j;
        if (r < n_rows) out[(size_t)r * 64 + c] = __float2bfloat16(acc[j]);
    }
}

// ---------------- fused GCN aggregate: out[n] = bias + self + sum_in-edges ----------------
// 16 lanes per node; T is bf16 (8B = 4 feats per lane).
__global__ __launch_bounds__(NTHREADS) void gcn_aggregate(
    const __hip_bfloat16* __restrict__ T, float* __restrict__ out,
    const float* __restrict__ dis, const float* __restrict__ bias,
    const int* __restrict__ row_ptr, const int2* __restrict__ adj, int n) {
    int node = (blockIdx.x * NTHREADS + threadIdx.x) >> 4;
    int q = threadIdx.x & 15;
    if (node >= n) return;

    const ushort4* T4 = (const ushort4*)T;  // 4 bf16 per load
    float4 b = ((const float4*)bias)[q];
    float dn = dis[node];
    float s2 = dn * dn;

    ushort4 sv = T4[(size_t)node * 16 + q];
    float4 acc;
    acc.x = b.x + __uint_as_float((uint32)sv.x << 16) * s2;
    acc.y = b.y + __uint_as_float((uint32)sv.y << 16) * s2;
    acc.z = b.z + __uint_as_float((uint32)sv.z << 16) * s2;
    acc.w = b.w + __uint_as_float((uint32)sv.w << 16) * s2;

    int e0 = row_ptr[node];
    int e1 = row_ptr[node + 1];
    int e = e0;
    for (; e + 1 < e1; e += 2) {
        int2 a0 = adj[e];
        int2 a1 = adj[e + 1];
        float w0 = __int_as_float(a0.y);
        float w1 = __int_as_float(a1.y);
        ushort4 t0 = T4[(size_t)a0.x * 16 + q];
        ushort4 t1 = T4[(size_t)a1.x * 16 + q];
        acc.x += __uint_as_float((uint32)t0.x << 16) * w0;
        acc.y += __uint_as_float((uint32)t0.y << 16) * w0;
        acc.z += __uint_as_float((uint32)t0.z << 16) * w0;
        acc.w += __uint_as_float((uint32)t0.w << 16) * w0;
        acc.x += __uint_as_float((uint32)t1.x << 16) * w1;
        acc.y += __uint_as_float((uint32)t1.y << 16) * w1;
        acc.z += __uint_as_float((uint32)t1.z << 16) * w1;
        acc.w += __uint_as_float((uint32)t1.w << 16) * w1;
    }
    if (e < e1) {
        int2 a0 = adj[e];
        float w0 = __int_as_float(a0.y);
        ushort4 t0 = T4[(size_t)a0.x * 16 + q];
        acc.x += __uint_as_float((uint32)t0.x << 16) * w0;
        acc.y += __uint_as_float((uint32)t0.y << 16) * w0;
        acc.z += __uint_as_float((uint32)t0.z << 16) * w0;
        acc.w += __uint_as_float((uint32)t0.w << 16) * w0;
    }
    ((float4*)out)[(size_t)node * 16 + q] = acc;
}

// ---------------- pooling: 128 nodes/block, register run-length, global atomics ----------------
__global__ __launch_bounds__(NTHREADS) void pool_kernel(
    const float* __restrict__ h, const int* __restrict__ gid,
    float* __restrict__ pooled, int n) {
    int t = threadIdx.x;
    int q = t & 15;    // float4 slot
    int w = t >> 4;    // 0..15 node lane
    int base = blockIdx.x * 128;

    float4 racc = make_float4(0.f, 0.f, 0.f, 0.f);
    int cur = -1;
#pragma unroll
    for (int i = 0; i < 8; i++) {
        int node = base + i * 16 + w;
        if (node < n) {
            int g = gid[node];
            if (g != cur) {
                if (cur >= 0) {
                    float* p = pooled + cur * 64 + q * 4;
                    if (racc.x != 0.f) atomicAdd(p + 0, racc.x);
                    if (racc.y != 0.f) atomicAdd(p + 1, racc.y);
                    if (racc.z != 0.f) atomicAdd(p + 2, racc.z);
                    if (racc.w != 0.f) atomicAdd(p + 3, racc.w);
                }
                racc = make_float4(0.f, 0.f, 0.f, 0.f);
                cur = g;
            }
            float4 v = ((const float4*)h)[(size_t)node * 16 + q];
            racc.x += fmaxf(v.x, 0.f);
            racc.y += fmaxf(v.y, 0.f);
            racc.z += fmaxf(v.z, 0.f);
            racc.w += fmaxf(v.w, 0.f);
        }
    }
    if (cur >= 0) {
        float* p = pooled + cur * 64 + q * 4;
        if (racc.x != 0.f) atomicAdd(p + 0, racc.x);
        if (racc.y != 0.f) atomicAdd(p + 1, racc.y);
        if (racc.z != 0.f) atomicAdd(p + 2, racc.z);
        if (racc.w != 0.f) atomicAdd(p + 3, racc.w);
    }
}

// ---------------- head MLP (one block) ----------------
__global__ __launch_bounds__(NTHREADS) void head_kernel(
    const float* __restrict__ pooled, const float* __restrict__ gf,
    const float* __restrict__ glob_w, const float* __restrict__ glob_b,
    const float* __restrict__ lin1_w, const float* __restrict__ lin1_b,
    const float* __restrict__ lin2_w, const float* __restrict__ lin2_b,
    const float* __restrict__ lin3_w, const float* __restrict__ lin3_b,
    const float* __restrict__ lin4_w, const float* __restrict__ lin4_b,
    float* __restrict__ out) {
    __shared__ float gx[64 * 32];
    __shared__ float zA[64 * 64];
    __shared__ float zB[64 * 64];
    int t = threadIdx.x;

    for (int i = t; i < 64 * 32; i += NTHREADS) {
        int g = i >> 5, j = i & 31;
        float acc = glob_b[j];
        for (int k = 0; k < 32; k++) acc += gf[g * 32 + k] * glob_w[k * 32 + j];
        gx[i] = fmaxf(acc, 0.f);
    }
    for (int i = t; i < 4096; i += NTHREADS) {
        int g = i >> 6, j = i & 63;
        float acc = lin1_b[j];
        for (int k = 0; k < 64; k++) acc += pooled[g * 64 + k] * lin1_w[k * 64 + j];
        zA[i] = fmaxf(acc, 0.f);
    }
    __syncthreads();
    for (int i = t; i < 4096; i += NTHREADS) {
        int g = i >> 6, j = i & 63;
        float acc = lin2_b[j];
        for (int k = 0; k < 64; k++) acc += zA[g * 64 + k] * lin2_w[k * 64 + j];
        for (int k = 0; k < 32; k++) acc += gx[g * 32 + k] * lin2_w[(64 + k) * 64 + j];
        zB[i] = fmaxf(acc, 0.f);
    }
    __syncthreads();
    for (int i = t; i < 4096; i += NTHREADS) {
        int g = i >> 6, j = i & 63;
        float acc = lin3_b[j];
        for (int k = 0; k < 64; k++) acc += zB[g * 64 + k] * lin3_w[k * 64 + j];
        zA[i] = fmaxf(acc, 0.f);
    }
    __syncthreads();
    if (t < 64) {
        float acc = lin4_b[0];
        for (int k = 0; k < 64; k++) acc += zA[t * 64 + k] * lin4_w[k];
        out[t] = acc;
    }
}

extern "C" void kernel_launch(void* const* d_in, const int* in_sizes, int n_in,
                              void* d_out, int out_size, void* d_ws, size_t ws_size,
                              hipStream_t stream) {
    const float* x      = (const float*)d_in[0];
    const float* gf     = (const float*)d_in[1];
    const float* conv_w[3] = {(const float*)d_in[2], (const float*)d_in[4], (const float*)d_in[6]};
    const float* conv_b[3] = {(const float*)d_in[3], (const float*)d_in[5], (const float*)d_in[7]};
    const float* lin1_w = (const float*)d_in[8];
    const float* lin1_b = (const float*)d_in[9];
    const float* glob_w = (const float*)d_in[10];
    const float* glob_b = (const float*)d_in[11];
    const float* lin2_w = (const float*)d_in[12];
    const float* lin2_b = (const float*)d_in[13];
    const float* lin3_w = (const float*)d_in[14];
    const float* lin3_b = (const float*)d_in[15];
    const float* lin4_w = (const float*)d_in[16];
    const float* lin4_b = (const float*)d_in[17];
    const int* ei  = (const int*)d_in[18];
    const int* gid = (const int*)d_in[19];

    const int N = in_sizes[0] / 64;   // 100000
    const int E = in_sizes[18] / 2;   // 1600000

    // workspace layout (keep every segment 16B-aligned)
    char* ws = (char*)d_ws;
    float* dis     = (float*)ws;                 ws += (size_t)N * 4;
    float* pooled  = (float*)ws;                 ws += 4096 * 4;
    __hip_bfloat16* T = (__hip_bfloat16*)ws;     ws += (size_t)N * 64 * 2;
    float* A       = (float*)ws;                 ws += (size_t)N * 64 * 4;
    int*   degi    = (int*)ws;                   ws += (size_t)N * 4;
    int*   row_ptr = (int*)ws;                   ws += ((size_t)N + 4) * 4;
    int*   cursor  = (int*)ws;                   ws += (size_t)N * 4;
    int2*  adj     = (int2*)ws;                  ws += (size_t)E * 8;
    int*   bsums   = (int*)ws;                   ws += 512 * 4;

    const int nb_N  = (N + NTHREADS - 1) / NTHREADS;
    const int nb_E2 = (E / 2 + NTHREADS - 1) / NTHREADS;
    const int nb_E4 = (E / 4 + NTHREADS - 1) / NTHREADS;
    const int nb_sc = (N + 1023) / 1024;

    // ---- CSR build ----
    hipMemsetAsync(degi, 0, (size_t)N * 4, stream);
    hist_dst<<<nb_E2, NTHREADS, 0, stream>>>(degi, ei, E);
    dis_kernel<<<nb_N, NTHREADS, 0, stream>>>(degi, dis, N);
    scan1<<<nb_sc, NTHREADS, 0, stream>>>(degi, row_ptr, bsums, N);
    scan2<<<1, 64, 0, stream>>>(bsums, nb_sc);
    scan3<<<nb_N, NTHREADS, 0, stream>>>(row_ptr, cursor, bsums, N, E);
    bucket<<<nb_E4, NTHREADS, 0, stream>>>(ei, dis, cursor, adj, E);

    const int gemm_blocks = (N + 63) / 64;
    const int agg_blocks  = (N * 16 + NTHREADS - 1) / NTHREADS;

    // layer 0: x -> T -> A
    gemm64<<<gemm_blocks, NTHREADS, 0, stream>>>(x, T, conv_w[0], N, 0);
    gcn_aggregate<<<agg_blocks, NTHREADS, 0, stream>>>(T, A, dis, conv_b[0], row_ptr, adj, N);

    // layer 1: relu(A) -> T -> A
    gemm64<<<gemm_blocks, NTHREADS, 0, stream>>>(A, T, conv_w[1], N, 1);
    gcn_aggregate<<<agg_blocks, NTHREADS, 0, stream>>>(T, A, dis, conv_b[1], row_ptr, adj, N);

    // layer 2: relu(A) -> T -> A
    gemm64<<<gemm_blocks, NTHREADS, 0, stream>>>(A, T, conv_w[2], N, 1);
    gcn_aggregate<<<agg_blocks, NTHREADS, 0, stream>>>(T, A, dis, conv_b[2], row_ptr, adj, N);

    // pooling (applies relu to conv2 output)
    hipMemsetAsync(pooled, 0, 4096 * 4, stream);
    pool_kernel<<<(N + 127) / 128, NTHREADS, 0, stream>>>(A, gid, pooled, N);

    // head MLP
    head_kernel<<<1, NTHREADS, 0, stream>>>(pooled, gf,
                                            glob_w, glob_b, lin1_w, lin1_b,
                                            lin2_w, lin2_b, lin3_w, lin3_b,
                                            lin4_w, lin4_b, (float*)d_out);
}